// Round 10
// baseline (155.365 us; speedup 1.0000x reference)
//
#include <hip/hip_runtime.h>
#include <hip/hip_bf16.h>
#include <cstdint>

typedef short short8 __attribute__((ext_vector_type(8)));
typedef float f32x4 __attribute__((ext_vector_type(4)));

#define OUT0_SZ  (2*4096*1024)       // 8388608
#define OUT1_OFF OUT0_SZ             // 8388608
#define OUT2_OFF (OUT0_SZ + 2*4096*64) // 8912896

__device__ __forceinline__ unsigned short f2bf(float f) {
    unsigned u = __float_as_uint(f);
    unsigned r = (u + 0x7FFFu + ((u >> 16) & 1u)) >> 16;
    return (unsigned short)r;
}

// ---------------------------------------------------------------------------
// Kernel 1: PREP (fused, block-role split; all roles independent)
//   blocks    0..1023: gather embed rows -> bf16 Ag[4096][512]
//   blocks 1024..1535: transpose W_code -> bf16 Wt[1024][512]
//   blocks 1536..1599: bias[b][d] = b[d]+cond@W_cond+spk@W_spk (split-K)
// ---------------------------------------------------------------------------
__global__ __launch_bounds__(256) void prep_kernel(
    const float* __restrict__ embed, const int* __restrict__ code,
    const float* __restrict__ cond, const float* __restrict__ spk,
    const float* __restrict__ W, const float* __restrict__ bvec,
    unsigned short* __restrict__ Ag, unsigned short* __restrict__ Wt,
    float* __restrict__ bias)
{
    __shared__ float tile[32][33];   // transpose role
    __shared__ float red[8][32];     // bias role
    const int bid = blockIdx.x;

    if (bid < 1024) {
        // ---- gather: one bf16x8 chunk per thread ----
        int gtid = bid * 256 + threadIdx.x;      // 0..262143
        int r = gtid >> 6;                       // 0..4095
        int c = (gtid & 63) * 8;
        int cv = code[r];
        const float* s = embed + (size_t)cv * 512 + c;
        float4 f0 = *(const float4*)s;
        float4 f1 = *(const float4*)(s + 4);
        short8 v;
        v[0] = (short)f2bf(f0.x); v[1] = (short)f2bf(f0.y);
        v[2] = (short)f2bf(f0.z); v[3] = (short)f2bf(f0.w);
        v[4] = (short)f2bf(f1.x); v[5] = (short)f2bf(f1.y);
        v[6] = (short)f2bf(f1.z); v[7] = (short)f2bf(f1.w);
        *(short8*)&Ag[(size_t)r * 512 + c] = v;
    } else if (bid < 1536) {
        // ---- transpose W rows 512..1023 -> Wt[1024][512] ----
        int idx = bid - 1024;                    // 0..511
        int k0 = (idx & 15) * 32;
        int n0 = (idx >> 4) * 32;
        int lx = threadIdx.x & 31;
        int ly = threadIdx.x >> 5;
        #pragma unroll
        for (int rr = 0; rr < 32; rr += 8)
            tile[ly + rr][lx] = W[(size_t)(512 + k0 + ly + rr) * 1024 + n0 + lx];
        __syncthreads();
        #pragma unroll
        for (int rr = 0; rr < 32; rr += 8)
            Wt[(size_t)(n0 + ly + rr) * 512 + k0 + lx] = f2bf(tile[lx][ly + rr]);
    } else {
        // ---- bias: 64 blocks, (2b x 32 d-chunks) x (8-way ksplit x 32 d) ----
        int idx = bid - 1536;
        const int b  = idx >> 5;
        const int d0 = (idx & 31) * 32;
        const int dl = threadIdx.x & 31;
        const int ks = threadIdx.x >> 5;
        const int d  = d0 + dl;
        const float* condb = cond + b * 512;
        const float* spkb  = spk + b * 192;
        float acc = 0.f;
        #pragma unroll 8
        for (int i = 0; i < 64; ++i) {
            int k = ks * 64 + i;
            acc = fmaf(condb[k], W[(size_t)k * 1024 + d], acc);
        }
        #pragma unroll 8
        for (int i = 0; i < 24; ++i) {
            int s = ks * 24 + i;
            acc = fmaf(spkb[s], W[(size_t)(1024 + s) * 1024 + d], acc);
        }
        red[ks][dl] = acc;
        __syncthreads();
        if (ks == 0) {
            float t = acc + bvec[d];
            #pragma unroll
            for (int j = 1; j < 8; ++j) t += red[j][dl];
            bias[b * 1024 + d] = t;
        }
    }
}

// ---------------------------------------------------------------------------
// Kernel 2: MAIN (fused, block-role split; gemm blocks dispatched first so
// compute starts immediately while mask/rope blocks saturate HBM writes)
//   blocks    0..255 : GEMM 128x128 tile (math identical to round-9 version)
//   blocks  256..1279: rope (f64 sincos, float2 store)
//   blocks 1280..5375: mask (4x float4 = 64 contiguous B per thread)
// ---------------------------------------------------------------------------
__global__ __launch_bounds__(256) void main_kernel(
    const unsigned short* __restrict__ Ag, const unsigned short* __restrict__ Wt,
    const float* __restrict__ bias, float* __restrict__ out0,
    float* __restrict__ out1, float* __restrict__ out2)
{
    __shared__ short8 AsV[128 * 64 / 8];
    __shared__ short8 BsV[128 * 64 / 8];
    const int bid = blockIdx.x;

    if (bid < 256) {
        // ================= GEMM =================
        unsigned short* As = (unsigned short*)AsV;
        unsigned short* Bs = (unsigned short*)BsV;
        const int tid = threadIdx.x;
        const int bm = bid >> 3;     // 0..31
        const int bn = bid & 7;      // 0..7
        const int lane = tid & 63;
        const int wid = tid >> 6;
        const int wr = wid >> 1;
        const int wc = wid & 1;
        const int l15 = lane & 15;
        const int l4  = lane >> 4;

        f32x4 acc[4][4];
        #pragma unroll
        for (int i = 0; i < 4; ++i)
            #pragma unroll
            for (int j = 0; j < 4; ++j)
                acc[i][j] = (f32x4){0.f, 0.f, 0.f, 0.f};

        long a_off[4]; long b_off[4]; int dst[4];
        #pragma unroll
        for (int i = 0; i < 4; ++i) {
            int ch = i * 256 + tid;
            int r  = ch >> 3;
            int kc = (ch & 7) * 8;
            a_off[i] = (long)(bm * 128 + r) * 512 + kc;
            b_off[i] = (long)(bn * 128 + r) * 512 + kc;
            dst[i]   = r * 64 + (kc ^ ((r & 7) << 3));
        }

        for (int kt = 0; kt < 512; kt += 64) {
            __syncthreads();
            #pragma unroll
            for (int i = 0; i < 4; ++i)
                *(short8*)&As[dst[i]] = *(const short8*)&Ag[a_off[i] + kt];
            #pragma unroll
            for (int i = 0; i < 4; ++i)
                *(short8*)&Bs[dst[i]] = *(const short8*)&Wt[b_off[i] + kt];
            __syncthreads();
            #pragma unroll
            for (int ks = 0; ks < 2; ++ks) {
                const int kb = ks * 32 + l4 * 8;
                short8 af[4], bf[4];
                #pragma unroll
                for (int mi = 0; mi < 4; ++mi) {
                    int r = wr * 64 + mi * 16 + l15;
                    af[mi] = *(const short8*)&As[r * 64 + (kb ^ ((r & 7) << 3))];
                }
                #pragma unroll
                for (int ni = 0; ni < 4; ++ni) {
                    int n = wc * 64 + ni * 16 + l15;
                    bf[ni] = *(const short8*)&Bs[n * 64 + (kb ^ ((n & 7) << 3))];
                }
                #pragma unroll
                for (int mi = 0; mi < 4; ++mi)
                    #pragma unroll
                    for (int ni = 0; ni < 4; ++ni)
                        acc[mi][ni] = __builtin_amdgcn_mfma_f32_16x16x32_bf16(
                            af[mi], bf[ni], acc[mi][ni], 0, 0, 0);
            }
        }

        const int b = bm >> 4;
        const float* biasb = bias + b * 1024;
        #pragma unroll
        for (int ni = 0; ni < 4; ++ni) {
            const int n = bn * 128 + wc * 64 + ni * 16 + l15;
            const float bv = biasb[n];
            #pragma unroll
            for (int mi = 0; mi < 4; ++mi) {
                const int mbase = bm * 128 + wr * 64 + mi * 16 + l4 * 4;
                #pragma unroll
                for (int j = 0; j < 4; ++j) {
                    const int u = (mbase + j) & 2047;
                    const size_t o = ((size_t)(b * 4096 + 2 * u)) * 1024 + n;
                    const float v = acc[mi][ni][j] + bv;
                    out0[o] = v;
                    out0[o + 1024] = v;
                }
            }
        }
    } else if (bid < 1280) {
        // ================= ROPE =================
        int tid = (bid - 256) * 256 + threadIdx.x;   // 0..262143
        int kk = tid & 31;
        int t  = (tid >> 5) & 4095;
        int c  = tid >> 17;
        double theta = exp2(-(double)kk * 0.41524101186092028); // 10000^(-k/32)
        double a = (double)t * theta;
        float vf = (float)(c ? sin(a) : cos(a));
        float2 w; w.x = vf; w.y = vf;
        *(float2*)&out1[(size_t)(c * 4096 + t) * 64 + kk * 2] = w;
    } else {
        // ================= MASK =================
        // 4096 blocks x 256 threads x 4 float4 (64 contiguous B per thread)
        int q0 = (bid - 1280) * 1024 + threadIdx.x * 4;
        #pragma unroll
        for (int s = 0; s < 4; ++s) {
            int q = q0 + s;
            int i = q >> 10;
            int j = (q & 1023) << 2;
            int bi = i / 24;
            float4 v;
            v.x = (float)((j    ) / 24 - bi);
            v.y = (float)((j + 1) / 24 - bi);
            v.z = (float)((j + 2) / 24 - bi);
            v.w = (float)((j + 3) / 24 - bi);
            ((float4*)out2)[q] = v;
        }
    }
}

// ---------------------------------------------------------------------------
extern "C" void kernel_launch(void* const* d_in, const int* in_sizes, int n_in,
                              void* d_out, int out_size, void* d_ws, size_t ws_size,
                              hipStream_t stream) {
    const float* cond  = (const float*)d_in[0];
    const float* spk   = (const float*)d_in[1];
    const int*   code  = (const int*)d_in[2];
    const float* embed = (const float*)d_in[3];
    const float* W     = (const float*)d_in[4];
    const float* bvec  = (const float*)d_in[5];

    float* out  = (float*)d_out;
    float* out0 = out;
    float* out1 = out + OUT1_OFF;
    float* out2 = out + OUT2_OFF;

    float* bias = (float*)d_ws;                                   // 8 KB
    unsigned short* Wt = (unsigned short*)((char*)d_ws + 8192);   // 1 MB
    unsigned short* Ag = (unsigned short*)((char*)d_ws + 8192 + 1048576); // 4 MB

    prep_kernel<<<1600, 256, 0, stream>>>(embed, code, cond, spk, W, bvec,
                                          Ag, Wt, bias);
    main_kernel<<<5376, 256, 0, stream>>>(Ag, Wt, bias, out0, out1, out2);
}

// Round 11
// 152.958 us; speedup vs baseline: 1.0157x; 1.0157x over previous
//
#include <hip/hip_runtime.h>
#include <hip/hip_bf16.h>
#include <cstdint>

typedef short short8 __attribute__((ext_vector_type(8)));
typedef float f32x4 __attribute__((ext_vector_type(4)));

#define OUT0_SZ  (2*4096*1024)         // 8388608
#define OUT1_OFF OUT0_SZ               // 8388608
#define OUT2_OFF (OUT0_SZ + 2*4096*64) // 8912896

__device__ __forceinline__ unsigned short f2bf(float f) {
    unsigned u = __float_as_uint(f);
    unsigned r = (u + 0x7FFFu + ((u >> 16) & 1u)) >> 16;
    return (unsigned short)r;
}

// async global->LDS, 16B per lane; LDS dst = wave-uniform base + lane*16
#define GLOAD_LDS(gp, lp)                                                     \
    __builtin_amdgcn_global_load_lds(                                         \
        (const __attribute__((address_space(1))) void*)(gp),                  \
        (__attribute__((address_space(3))) void*)(lp), 16, 0, 0)

// ---------------------------------------------------------------------------
// Kernel 1: PREP (block-role split). Ag/Wt are written PRE-SWIZZLED:
// within each BK=64 block, 8-elem chunk cb of row r is stored at chunk
// position cb ^ (r&7). GEMM then stages LINEARLY (global_load_lds) and
// reads with the same XOR (rule 21: linear dst + pre-swz source + swz read).
//   blocks    0..1023: gather embed rows -> bf16 Ag[4096][512] (swizzled)
//   blocks 1024..1535: transpose W_code  -> bf16 Wt[1024][512] (swizzled)
//   blocks 1536..1599: bias = b + cond@W_cond + spk@W_spk (split-K)
// ---------------------------------------------------------------------------
__global__ __launch_bounds__(256) void prep_kernel(
    const float* __restrict__ embed, const int* __restrict__ code,
    const float* __restrict__ cond, const float* __restrict__ spk,
    const float* __restrict__ W, const float* __restrict__ bvec,
    unsigned short* __restrict__ Ag, unsigned short* __restrict__ Wt,
    float* __restrict__ bias)
{
    __shared__ float tile[32][33];
    __shared__ float red[8][32];
    const int bid = blockIdx.x;

    if (bid < 1024) {
        // ---- gather: one bf16x8 chunk per thread, swizzled dst chunk ----
        int gtid = bid * 256 + threadIdx.x;      // 0..262143
        int r = gtid >> 6;                       // 0..4095
        int c = gtid & 63;                       // chunk 0..63
        int cv = code[r];
        const float* s = embed + (size_t)cv * 512 + c * 8;
        float4 f0 = *(const float4*)s;
        float4 f1 = *(const float4*)(s + 4);
        short8 v;
        v[0] = (short)f2bf(f0.x); v[1] = (short)f2bf(f0.y);
        v[2] = (short)f2bf(f0.z); v[3] = (short)f2bf(f0.w);
        v[4] = (short)f2bf(f1.x); v[5] = (short)f2bf(f1.y);
        v[6] = (short)f2bf(f1.z); v[7] = (short)f2bf(f1.w);
        int csw = (c & ~7) | ((c & 7) ^ (r & 7));
        *(short8*)&Ag[(size_t)r * 512 + csw * 8] = v;
    } else if (bid < 1536) {
        // ---- transpose W rows 512..1023 -> Wt[1024][512], swizzled col ----
        int idx = bid - 1024;                    // 0..511
        int k0 = (idx & 15) * 32;
        int n0 = (idx >> 4) * 32;
        int lx = threadIdx.x & 31;
        int ly = threadIdx.x >> 5;
        #pragma unroll
        for (int rr = 0; rr < 32; rr += 8)
            tile[ly + rr][lx] = W[(size_t)(512 + k0 + ly + rr) * 1024 + n0 + lx];
        __syncthreads();
        #pragma unroll
        for (int rr = 0; rr < 32; rr += 8) {
            int n = n0 + ly + rr;
            int k = k0 + lx;
            int ksw = (k & ~63) | ((((k >> 3) & 7) ^ (n & 7)) << 3) | (k & 7);
            Wt[(size_t)n * 512 + ksw] = f2bf(tile[lx][ly + rr]);
        }
    } else {
        // ---- bias: 64 blocks, (2b x 32 d-chunks) x (8-way ksplit x 32 d) ----
        int idx = bid - 1536;
        const int b  = idx >> 5;
        const int d0 = (idx & 31) * 32;
        const int dl = threadIdx.x & 31;
        const int ks = threadIdx.x >> 5;
        const int d  = d0 + dl;
        const float* condb = cond + b * 512;
        const float* spkb  = spk + b * 192;
        float acc = 0.f;
        #pragma unroll 8
        for (int i = 0; i < 64; ++i) {
            int k = ks * 64 + i;
            acc = fmaf(condb[k], W[(size_t)k * 1024 + d], acc);
        }
        #pragma unroll 8
        for (int i = 0; i < 24; ++i) {
            int s = ks * 24 + i;
            acc = fmaf(spkb[s], W[(size_t)(1024 + s) * 1024 + d], acc);
        }
        red[ks][dl] = acc;
        __syncthreads();
        if (ks == 0) {
            float t = acc + bvec[d];
            #pragma unroll
            for (int j = 1; j < 8; ++j) t += red[j][dl];
            bias[b * 1024 + d] = t;
        }
    }
}

// ---------------------------------------------------------------------------
// Kernel 2: MAIN (block-role split)
//   blocks    0..255 : GEMM 128x128, dbuf LDS + global_load_lds 2-phase pipe
//   blocks  256..1279: rope
//   blocks 1280..5375: mask
// ---------------------------------------------------------------------------
__global__ __launch_bounds__(256) void main_kernel(
    const unsigned short* __restrict__ Ag, const unsigned short* __restrict__ Wt,
    const float* __restrict__ bias, float* __restrict__ out0,
    float* __restrict__ out1, float* __restrict__ out2)
{
    __shared__ unsigned short AsX[2][128 * 64];   // 2 x 16 KB
    __shared__ unsigned short BsX[2][128 * 64];   // 2 x 16 KB
    const int bid = blockIdx.x;

    if (bid < 256) {
        // ================= GEMM =================
        const int tid = threadIdx.x;
        const int bm = bid >> 3;     // 0..31
        const int bn = bid & 7;      // 0..7
        const int lane = tid & 63;
        const int w   = tid >> 6;    // wave 0..3
        const int wr = w >> 1;
        const int wc = w & 1;
        const int l15 = lane & 15;
        const int l4  = lane >> 4;
        const int sub = lane >> 3;   // 0..7 (row within 8-row issue group)
        const int chk = lane & 7;    // chunk 0..7

        const unsigned short* Asrc = Ag + (size_t)(bm * 128) * 512;
        const unsigned short* Bsrc = Wt + (size_t)(bn * 128) * 512;

        f32x4 acc[4][4];
        #pragma unroll
        for (int i = 0; i < 4; ++i)
            #pragma unroll
            for (int j = 0; j < 4; ++j)
                acc[i][j] = (f32x4){0.f, 0.f, 0.f, 0.f};

        // per-lane global element offsets for the 4 issue groups
        size_t goff[4];
        #pragma unroll
        for (int i = 0; i < 4; ++i) {
            int rg = (w * 4 + i) * 8 + sub;            // tile row 0..127
            goff[i] = (size_t)rg * 512 + chk * 8;
        }

        // prologue: stage tile kt=0 into buf 0
        #pragma unroll
        for (int i = 0; i < 4; ++i) {
            GLOAD_LDS(Asrc + goff[i], &AsX[0][(w * 4 + i) * 512]);
            GLOAD_LDS(Bsrc + goff[i], &BsX[0][(w * 4 + i) * 512]);
        }
        __syncthreads();   // drains vmcnt (compiler) + barrier

        int cur = 0;
        for (int t = 0; t < 8; ++t) {
            // issue next tile's async loads (overlap with compute below)
            if (t < 7) {
                const int kt = (t + 1) * 64;
                #pragma unroll
                for (int i = 0; i < 4; ++i) {
                    GLOAD_LDS(Asrc + goff[i] + kt, &AsX[cur ^ 1][(w * 4 + i) * 512]);
                    GLOAD_LDS(Bsrc + goff[i] + kt, &BsX[cur ^ 1][(w * 4 + i) * 512]);
                }
            }
            // compute current tile
            const unsigned short* As = AsX[cur];
            const unsigned short* Bs = BsX[cur];
            #pragma unroll
            for (int ks = 0; ks < 2; ++ks) {
                const int kb = ks * 32 + l4 * 8;
                short8 af[4], bf[4];
                #pragma unroll
                for (int mi = 0; mi < 4; ++mi) {
                    int r = wr * 64 + mi * 16 + l15;
                    af[mi] = *(const short8*)&As[r * 64 + (kb ^ ((r & 7) << 3))];
                }
                #pragma unroll
                for (int ni = 0; ni < 4; ++ni) {
                    int n = wc * 64 + ni * 16 + l15;
                    bf[ni] = *(const short8*)&Bs[n * 64 + (kb ^ ((n & 7) << 3))];
                }
                #pragma unroll
                for (int mi = 0; mi < 4; ++mi)
                    #pragma unroll
                    for (int ni = 0; ni < 4; ++ni)
                        acc[mi][ni] = __builtin_amdgcn_mfma_f32_16x16x32_bf16(
                            af[mi], bf[ni], acc[mi][ni], 0, 0, 0);
            }
            __syncthreads();   // drain next-tile loads; protect buf reuse
            cur ^= 1;
        }

        // Epilogue: C/D col=lane&15, row=(lane>>4)*4+j. Row m -> t=2u,2u+1.
        const int b = bm >> 4;
        const float* biasb = bias + b * 1024;
        #pragma unroll
        for (int ni = 0; ni < 4; ++ni) {
            const int n = bn * 128 + wc * 64 + ni * 16 + l15;
            const float bv = biasb[n];
            #pragma unroll
            for (int mi = 0; mi < 4; ++mi) {
                const int mbase = bm * 128 + wr * 64 + mi * 16 + l4 * 4;
                #pragma unroll
                for (int j = 0; j < 4; ++j) {
                    const int u = (mbase + j) & 2047;
                    const size_t o = ((size_t)(b * 4096 + 2 * u)) * 1024 + n;
                    const float v = acc[mi][ni][j] + bv;
                    out0[o] = v;
                    out0[o + 1024] = v;
                }
            }
        }
    } else if (bid < 1280) {
        // ================= ROPE =================
        int tid = (bid - 256) * 256 + threadIdx.x;   // 0..262143
        int kk = tid & 31;
        int t  = (tid >> 5) & 4095;
        int c  = tid >> 17;
        double theta = exp2(-(double)kk * 0.41524101186092028); // 10000^(-k/32)
        double a = (double)t * theta;
        float vf = (float)(c ? sin(a) : cos(a));
        float2 wv; wv.x = vf; wv.y = vf;
        *(float2*)&out1[(size_t)(c * 4096 + t) * 64 + kk * 2] = wv;
    } else {
        // ================= MASK =================
        int q0 = (bid - 1280) * 1024 + threadIdx.x * 4;
        #pragma unroll
        for (int s = 0; s < 4; ++s) {
            int q = q0 + s;
            int i = q >> 10;
            int j = (q & 1023) << 2;
            int bi = i / 24;
            float4 v;
            v.x = (float)((j    ) / 24 - bi);
            v.y = (float)((j + 1) / 24 - bi);
            v.z = (float)((j + 2) / 24 - bi);
            v.w = (float)((j + 3) / 24 - bi);
            ((float4*)out2)[q] = v;
        }
    }
}

// ---------------------------------------------------------------------------
extern "C" void kernel_launch(void* const* d_in, const int* in_sizes, int n_in,
                              void* d_out, int out_size, void* d_ws, size_t ws_size,
                              hipStream_t stream) {
    const float* cond  = (const float*)d_in[0];
    const float* spk   = (const float*)d_in[1];
    const int*   code  = (const int*)d_in[2];
    const float* embed = (const float*)d_in[3];
    const float* W     = (const float*)d_in[4];
    const float* bvec  = (const float*)d_in[5];

    float* out  = (float*)d_out;
    float* out0 = out;
    float* out1 = out + OUT1_OFF;
    float* out2 = out + OUT2_OFF;

    float* bias = (float*)d_ws;                                   // 8 KB
    unsigned short* Wt = (unsigned short*)((char*)d_ws + 8192);   // 1 MB
    unsigned short* Ag = (unsigned short*)((char*)d_ws + 8192 + 1048576); // 4 MB

    prep_kernel<<<1600, 256, 0, stream>>>(embed, code, cond, spk, W, bvec,
                                          Ag, Wt, bias);
    main_kernel<<<5376, 256, 0, stream>>>(Ag, Wt, bias, out0, out1, out2);
}